// Round 1
// baseline (34.931 us; speedup 1.0000x reference)
//
#include <hip/hip_runtime.h>

#define IMG_H 720
#define IMG_W 1280
#define IMG_N 2

// Bilateral filter, K=7, zero-padded borders.
// w(dy,dx) = exp(-(v-c)^2 * 50 - (dy^2+dx^2)/50), out = sum(w*v)/sum(w)
__global__ __launch_bounds__(256) void bilateral_kernel(
    const float* __restrict__ I, float* __restrict__ O) {
    int idx = blockIdx.x * blockDim.x + threadIdx.x;
    const int total = IMG_N * IMG_H * IMG_W;
    if (idx >= total) return;

    int x = idx % IMG_W;
    int y = (idx / IMG_W) % IMG_H;
    int n = idx / (IMG_W * IMG_H);

    const float* img = I + n * (IMG_H * IMG_W);
    float c = img[y * IMG_W + x];

    float wsum = 0.0f;
    float iwsum = 0.0f;

    // log2(e) folded in so we can use exp2-style fast exp via __expf:
    // __expf(x) on gfx9 compiles to v_mul + v_exp_f32; we just pass the
    // natural-log exponent and let the intrinsic handle conversion.
#pragma unroll
    for (int dy = -3; dy <= 3; ++dy) {
        int yy = y + dy;
        bool yok = (yy >= 0) && (yy < IMG_H);
        const float* row = img + yy * IMG_W;
#pragma unroll
        for (int dx = -3; dx <= 3; ++dx) {
            int xx = x + dx;
            // compile-time spatial term: -(dy^2+dx^2)/50
            const float spatial = -(float)(dy * dy + dx * dx) / 50.0f;
            float v = 0.0f;
            if (yok && xx >= 0 && xx < IMG_W) v = row[xx];
            float d = v - c;
            // exponent = -50*d^2 + spatial
            float e = fmaf(d * d, -50.0f, spatial);
            float w = __expf(e);
            wsum += w;
            iwsum = fmaf(w, v, iwsum);
        }
    }

    O[idx] = iwsum / wsum;
}

extern "C" void kernel_launch(void* const* d_in, const int* in_sizes, int n_in,
                              void* d_out, int out_size, void* d_ws, size_t ws_size,
                              hipStream_t stream) {
    const float* I = (const float*)d_in[0];
    float* O = (float*)d_out;
    const int total = IMG_N * IMG_H * IMG_W;
    const int block = 256;
    const int grid = (total + block - 1) / block;
    bilateral_kernel<<<grid, block, 0, stream>>>(I, O);
}